// Round 2
// baseline (1415.381 us; speedup 1.0000x reference)
//
#include <hip/hip_runtime.h>

#define D 128

// --- Kernel 1: transpose W[o][k] -> Wt[k][o] so GEMM can read 4 consecutive
// outputs per k with a single float4 load. Tiny (64 KB), uncoalesced write ok.
__global__ void transpose_W(const float* __restrict__ W, float* __restrict__ Wt) {
    int idx = blockIdx.x * blockDim.x + threadIdx.x;   // 0 .. D*D-1
    if (idx >= D * D) return;
    int o = idx / D;
    int k = idx - o * D;
    Wt[k * D + o] = W[idx];
}

// --- Kernel 2: h = x @ W^T + b.
// Block: 256 threads -> 32 rows x 128 outputs. Thread: 4 rows x 4 outputs.
// Per k-chunk of 4: 4 float4 Wt loads + 4 float4 x loads -> 64 FMAs.
// x loads are same-address across the 32 lanes of an o-group (HW broadcast);
// Wt (64 KB) stays L1/L2 resident.
__global__ __launch_bounds__(256) void gemm_xWt(
    const float* __restrict__ x, const float* __restrict__ Wt,
    const float* __restrict__ b, float* __restrict__ h, int n_rows) {
    const int t  = threadIdx.x;
    const int og = t & 31;          // output group: o0 = 4*og
    const int rg = t >> 5;          // row group 0..7
    const int o0 = og * 4;
    const int r0 = blockIdx.x * 32 + rg * 4;

    float acc[4][4] = {};

    for (int k = 0; k < D; k += 4) {
        float4 w0 = *(const float4*)&Wt[(k + 0) * D + o0];
        float4 w1 = *(const float4*)&Wt[(k + 1) * D + o0];
        float4 w2 = *(const float4*)&Wt[(k + 2) * D + o0];
        float4 w3 = *(const float4*)&Wt[(k + 3) * D + o0];
#pragma unroll
        for (int r = 0; r < 4; ++r) {
            int row = r0 + r;
            if (row >= n_rows) break;
            float4 xv = *(const float4*)&x[row * D + k];
            acc[r][0] += xv.x * w0.x + xv.y * w1.x + xv.z * w2.x + xv.w * w3.x;
            acc[r][1] += xv.x * w0.y + xv.y * w1.y + xv.z * w2.y + xv.w * w3.y;
            acc[r][2] += xv.x * w0.z + xv.y * w1.z + xv.z * w2.z + xv.w * w3.z;
            acc[r][3] += xv.x * w0.w + xv.y * w1.w + xv.z * w2.w + xv.w * w3.w;
        }
    }

    float4 bv = *(const float4*)&b[o0];
#pragma unroll
    for (int r = 0; r < 4; ++r) {
        int row = r0 + r;
        if (row >= n_rows) break;
        float4 hv;
        hv.x = acc[r][0] + bv.x;
        hv.y = acc[r][1] + bv.y;
        hv.z = acc[r][2] + bv.z;
        hv.w = acc[r][3] + bv.w;
        *(float4*)&h[row * D + o0] = hv;
    }
}

// --- Kernel 3: out[rows[e]] += vals[e] * h[cols[e]].
// 32 lanes per edge, 4 floats per lane. Gather of h[col] is a coalesced
// 512 B read per edge; writes are fp32 atomics (device scope, L2-side).
__global__ __launch_bounds__(256) void scatter_add(
    const int* __restrict__ rows, const int* __restrict__ cols,
    const float* __restrict__ vals, const float* __restrict__ h,
    float* __restrict__ out, int n_edges) {
    long long gid = (long long)blockIdx.x * blockDim.x + threadIdx.x;
    int e  = (int)(gid >> 5);
    if (e >= n_edges) return;
    int d4 = ((int)gid & 31) * 4;

    int   r = rows[e];
    int   c = cols[e];
    float v = vals[e];

    float4 hv = *(const float4*)&h[c * D + d4];
    float* op = &out[r * D + d4];
    atomicAdd(op + 0, v * hv.x);
    atomicAdd(op + 1, v * hv.y);
    atomicAdd(op + 2, v * hv.z);
    atomicAdd(op + 3, v * hv.w);
}

extern "C" void kernel_launch(void* const* d_in, const int* in_sizes, int n_in,
                              void* d_out, int out_size, void* d_ws, size_t ws_size,
                              hipStream_t stream) {
    const float* x    = (const float*)d_in[0];
    const int*   rows = (const int*)  d_in[1];
    const int*   cols = (const int*)  d_in[2];
    const float* vals = (const float*)d_in[3];
    const float* W    = (const float*)d_in[4];
    const float* b    = (const float*)d_in[5];
    float*       out  = (float*)d_out;

    const int n_nodes = in_sizes[0] / D;   // 50000
    const int n_edges = in_sizes[1];       // 800000

    // Workspace layout: Wt [D*D] floats, then h [n_nodes*D] floats (~25.7 MB).
    float* Wt = (float*)d_ws;
    float* h  = Wt + D * D;

    // Self-zero the output (harness poisons once, never re-poisons).
    hipMemsetAsync(d_out, 0, (size_t)n_nodes * D * sizeof(float), stream);

    transpose_W<<<(D * D + 255) / 256, 256, 0, stream>>>(W, Wt);

    gemm_xWt<<<(n_nodes + 31) / 32, 256, 0, stream>>>(x, Wt, b, h, n_nodes);

    long long scatter_threads = (long long)n_edges * 32;
    int scatter_blocks = (int)((scatter_threads + 255) / 256);
    scatter_add<<<scatter_blocks, 256, 0, stream>>>(rows, cols, vals, h, out, n_edges);
}

// Round 4
// 327.166 us; speedup vs baseline: 4.3262x; 4.3262x over previous
//
#include <hip/hip_runtime.h>

#define D 128
#define SCAN_THREADS 1024

// ---------------------------------------------------------------- W transpose
__global__ void transpose_W(const float* __restrict__ W, float* __restrict__ Wt) {
    int idx = blockIdx.x * blockDim.x + threadIdx.x;   // 0 .. D*D-1
    if (idx >= D * D) return;
    int o = idx / D;
    int k = idx - o * D;
    Wt[k * D + o] = W[idx];
}

// ---------------------------------------------------------------- h = xW^T + b
// 256 threads -> 32 rows x 128 outputs; thread: 4 rows x 4 outs, float4 loads.
__global__ __launch_bounds__(256) void gemm_xWt(
    const float* __restrict__ x, const float* __restrict__ Wt,
    const float* __restrict__ b, float* __restrict__ h, int n_rows) {
    const int t  = threadIdx.x;
    const int og = t & 31;
    const int rg = t >> 5;
    const int o0 = og * 4;
    const int r0 = blockIdx.x * 32 + rg * 4;

    float acc[4][4] = {};

    for (int k = 0; k < D; k += 4) {
        float4 w0 = *(const float4*)&Wt[(k + 0) * D + o0];
        float4 w1 = *(const float4*)&Wt[(k + 1) * D + o0];
        float4 w2 = *(const float4*)&Wt[(k + 2) * D + o0];
        float4 w3 = *(const float4*)&Wt[(k + 3) * D + o0];
#pragma unroll
        for (int r = 0; r < 4; ++r) {
            int row = r0 + r;
            if (row >= n_rows) break;
            float4 xv = *(const float4*)&x[row * D + k];
            acc[r][0] += xv.x * w0.x + xv.y * w1.x + xv.z * w2.x + xv.w * w3.x;
            acc[r][1] += xv.x * w0.y + xv.y * w1.y + xv.z * w2.y + xv.w * w3.y;
            acc[r][2] += xv.x * w0.z + xv.y * w1.z + xv.z * w2.z + xv.w * w3.z;
            acc[r][3] += xv.x * w0.w + xv.y * w1.w + xv.z * w2.w + xv.w * w3.w;
        }
    }

    float4 bv = *(const float4*)&b[o0];
#pragma unroll
    for (int r = 0; r < 4; ++r) {
        int row = r0 + r;
        if (row >= n_rows) break;
        float4 hv;
        hv.x = acc[r][0] + bv.x;
        hv.y = acc[r][1] + bv.y;
        hv.z = acc[r][2] + bv.z;
        hv.w = acc[r][3] + bv.w;
        *(float4*)&h[row * D + o0] = hv;
    }
}

// ---------------------------------------------------------------- CSR build
__global__ void hist_rows(const int* __restrict__ rows, int* __restrict__ counts,
                          int n_edges) {
    int i = blockIdx.x * blockDim.x + threadIdx.x;
    if (i < n_edges) atomicAdd(&counts[rows[i]], 1);
}

// Single-block exclusive scan over n counts -> offs[0..n], cursor copy.
__global__ __launch_bounds__(SCAN_THREADS) void scan_counts(
    const int* __restrict__ counts, int* __restrict__ offs,
    int* __restrict__ cursor, int n) {
    __shared__ int part[SCAN_THREADS];
    const int t = threadIdx.x;
    const int chunk = (n + SCAN_THREADS - 1) / SCAN_THREADS;
    const int s = t * chunk;
    const int e = min(s + chunk, n);

    int sum = 0;
    for (int i = s; i < e; ++i) sum += counts[i];
    part[t] = sum;
    __syncthreads();

    // in-place inclusive Hillis-Steele scan
    for (int off = 1; off < SCAN_THREADS; off <<= 1) {
        int add = (t >= off) ? part[t - off] : 0;
        __syncthreads();
        part[t] += add;
        __syncthreads();
    }

    int run = part[t] - sum;  // exclusive prefix for this chunk
    for (int i = s; i < e; ++i) {
        offs[i]   = run;
        cursor[i] = run;
        run += counts[i];
    }
    if (e == n) offs[n] = run;  // all such threads write the same total
}

// One index-atomic per edge; write {col,val} record in destination order.
__global__ void permute_edges(const int* __restrict__ rows,
                              const int* __restrict__ cols,
                              const float* __restrict__ vals,
                              int* __restrict__ cursor, int2* __restrict__ evec,
                              int n_edges) {
    int i = blockIdx.x * blockDim.x + threadIdx.x;
    if (i >= n_edges) return;
    int r   = rows[i];
    int pos = atomicAdd(&cursor[r], 1);
    evec[pos] = make_int2(cols[i], __float_as_int(vals[i]));
}

// ---------------------------------------------------------------- aggregate
// One wave (64 lanes) per node; lane owns float2 of the output row.
// Edge-record loads are wave-uniform (broadcast); h gathers are coalesced
// 512 B per edge; single plain store per node (no atomics, no out memset).
__global__ __launch_bounds__(256) void aggregate(
    const int* __restrict__ offs, const int2* __restrict__ evec,
    const float* __restrict__ h, float* __restrict__ out, int n_nodes) {
    int wid = blockIdx.x * (blockDim.x >> 6) + (threadIdx.x >> 6);
    if (wid >= n_nodes) return;
    int lane = threadIdx.x & 63;

    int s = offs[wid];
    int e = offs[wid + 1];
    float2 acc = make_float2(0.f, 0.f);

    int k = s;
    for (; k + 1 < e; k += 2) {
        int2 e0 = evec[k];
        int2 e1 = evec[k + 1];
        float2 h0 = *(const float2*)&h[(size_t)e0.x * D + lane * 2];
        float2 h1 = *(const float2*)&h[(size_t)e1.x * D + lane * 2];
        float v0 = __int_as_float(e0.y);
        float v1 = __int_as_float(e1.y);
        acc.x += v0 * h0.x; acc.y += v0 * h0.y;
        acc.x += v1 * h1.x; acc.y += v1 * h1.y;
    }
    if (k < e) {
        int2 e0 = evec[k];
        float2 h0 = *(const float2*)&h[(size_t)e0.x * D + lane * 2];
        float v0 = __int_as_float(e0.y);
        acc.x += v0 * h0.x; acc.y += v0 * h0.y;
    }

    *(float2*)&out[(size_t)wid * D + lane * 2] = acc;
}

// ---------------------------------------------------------------- fallback
__global__ __launch_bounds__(256) void scatter_add(
    const int* __restrict__ rows, const int* __restrict__ cols,
    const float* __restrict__ vals, const float* __restrict__ h,
    float* __restrict__ out, int n_edges) {
    long long gid = (long long)blockIdx.x * blockDim.x + threadIdx.x;
    int e  = (int)(gid >> 5);
    if (e >= n_edges) return;
    int d4 = ((int)gid & 31) * 4;
    int   r = rows[e];
    int   c = cols[e];
    float v = vals[e];
    float4 hv = *(const float4*)&h[c * D + d4];
    float* op = &out[r * D + d4];
    atomicAdd(op + 0, v * hv.x);
    atomicAdd(op + 1, v * hv.y);
    atomicAdd(op + 2, v * hv.z);
    atomicAdd(op + 3, v * hv.w);
}

// ---------------------------------------------------------------- launch
static inline size_t align16(size_t x) { return (x + 15) & ~(size_t)15; }

extern "C" void kernel_launch(void* const* d_in, const int* in_sizes, int n_in,
                              void* d_out, int out_size, void* d_ws, size_t ws_size,
                              hipStream_t stream) {
    const float* x    = (const float*)d_in[0];
    const int*   rows = (const int*)  d_in[1];
    const int*   cols = (const int*)  d_in[2];
    const float* vals = (const float*)d_in[3];
    const float* W    = (const float*)d_in[4];
    const float* b    = (const float*)d_in[5];
    float*       out  = (float*)d_out;

    const int n_nodes = in_sizes[0] / D;   // 50000
    const int n_edges = in_sizes[1];       // 800000

    // ---- workspace layout (16B-aligned regions)
    char*  base   = (char*)d_ws;
    size_t off    = 0;
    float* Wt     = (float*)(base + off); off = align16(off + (size_t)D * D * 4);
    float* h      = (float*)(base + off); off = align16(off + (size_t)n_nodes * D * 4);
    int*   counts = (int*)  (base + off); off = align16(off + (size_t)n_nodes * 4);
    int*   offs   = (int*)  (base + off); off = align16(off + ((size_t)n_nodes + 1) * 4);
    int*   cursor = (int*)  (base + off); off = align16(off + (size_t)n_nodes * 4);
    int2*  evec   = (int2*) (base + off); off = align16(off + (size_t)n_edges * 8);
    const bool csr_fits = (off <= ws_size);

    transpose_W<<<(D * D + 255) / 256, 256, 0, stream>>>(W, Wt);
    gemm_xWt<<<(n_nodes + 31) / 32, 256, 0, stream>>>(x, Wt, b, h, n_nodes);

    if (csr_fits) {
        hipMemsetAsync(counts, 0, (size_t)n_nodes * 4, stream);
        hist_rows<<<(n_edges + 255) / 256, 256, 0, stream>>>(rows, counts, n_edges);
        scan_counts<<<1, SCAN_THREADS, 0, stream>>>(counts, offs, cursor, n_nodes);
        permute_edges<<<(n_edges + 255) / 256, 256, 0, stream>>>(
            rows, cols, vals, cursor, evec, n_edges);
        aggregate<<<(n_nodes + 3) / 4, 256, 0, stream>>>(offs, evec, h, out, n_nodes);
    } else {
        hipMemsetAsync(d_out, 0, (size_t)n_nodes * D * sizeof(float), stream);
        long long scatter_threads = (long long)n_edges * 32;
        int scatter_blocks = (int)((scatter_threads + 255) / 256);
        scatter_add<<<scatter_blocks, 256, 0, stream>>>(rows, cols, vals, h, out, n_edges);
    }
}

// Round 5
// 229.824 us; speedup vs baseline: 6.1586x; 1.4236x over previous
//
#include <hip/hip_runtime.h>

#define D 128
#define SCAN_BLK 256
#define SCAN_THREADS 1024

// ---------------------------------------------------------------- W transpose
__global__ void transpose_W(const float* __restrict__ W, float* __restrict__ Wt) {
    int idx = blockIdx.x * blockDim.x + threadIdx.x;   // 0 .. D*D-1
    if (idx >= D * D) return;
    int o = idx / D;
    int k = idx - o * D;
    Wt[k * D + o] = W[idx];
}

// ---------------------------------------------------------------- h = xW^T + b
// 256 threads -> 32 rows x 128 outputs; thread: 4 rows x 4 outs, float4 loads.
__global__ __launch_bounds__(256) void gemm_xWt(
    const float* __restrict__ x, const float* __restrict__ Wt,
    const float* __restrict__ b, float* __restrict__ h, int n_rows) {
    const int t  = threadIdx.x;
    const int og = t & 31;
    const int rg = t >> 5;
    const int o0 = og * 4;
    const int r0 = blockIdx.x * 32 + rg * 4;

    float acc[4][4] = {};

    for (int k = 0; k < D; k += 4) {
        float4 w0 = *(const float4*)&Wt[(k + 0) * D + o0];
        float4 w1 = *(const float4*)&Wt[(k + 1) * D + o0];
        float4 w2 = *(const float4*)&Wt[(k + 2) * D + o0];
        float4 w3 = *(const float4*)&Wt[(k + 3) * D + o0];
#pragma unroll
        for (int r = 0; r < 4; ++r) {
            int row = r0 + r;
            if (row >= n_rows) break;
            float4 xv = *(const float4*)&x[row * D + k];
            acc[r][0] += xv.x * w0.x + xv.y * w1.x + xv.z * w2.x + xv.w * w3.x;
            acc[r][1] += xv.x * w0.y + xv.y * w1.y + xv.z * w2.y + xv.w * w3.y;
            acc[r][2] += xv.x * w0.z + xv.y * w1.z + xv.z * w2.z + xv.w * w3.z;
            acc[r][3] += xv.x * w0.w + xv.y * w1.w + xv.z * w2.w + xv.w * w3.w;
        }
    }

    float4 bv = *(const float4*)&b[o0];
#pragma unroll
    for (int r = 0; r < 4; ++r) {
        int row = r0 + r;
        if (row >= n_rows) break;
        float4 hv;
        hv.x = acc[r][0] + bv.x;
        hv.y = acc[r][1] + bv.y;
        hv.z = acc[r][2] + bv.z;
        hv.w = acc[r][3] + bv.w;
        *(float4*)&h[row * D + o0] = hv;
    }
}

// ---------------------------------------------------------------- CSR build
__global__ void hist_rows(const int* __restrict__ rows, int* __restrict__ counts,
                          int n_edges) {
    int i = blockIdx.x * blockDim.x + threadIdx.x;
    if (i < n_edges) atomicAdd(&counts[rows[i]], 1);
}

// ---- hierarchical scan: local (per-256-chunk) -> block sums -> add offsets
__global__ __launch_bounds__(SCAN_BLK) void scan_local(
    const int* __restrict__ counts, int* __restrict__ offs,
    int* __restrict__ blockSums, int n) {
    __shared__ int sh[SCAN_BLK];
    const int t = threadIdx.x;
    const int i = blockIdx.x * SCAN_BLK + t;
    int v = (i < n) ? counts[i] : 0;
    sh[t] = v;
    __syncthreads();
    for (int off = 1; off < SCAN_BLK; off <<= 1) {
        int add = (t >= off) ? sh[t - off] : 0;
        __syncthreads();
        sh[t] += add;
        __syncthreads();
    }
    if (i < n) offs[i] = sh[t] - v;               // exclusive local prefix
    if (t == SCAN_BLK - 1) blockSums[blockIdx.x] = sh[SCAN_BLK - 1];
}

// single block; nb <= 1024. Writes exclusive scan in place + grand total.
__global__ __launch_bounds__(1024) void scan_blocks(
    int* __restrict__ blockSums, int* __restrict__ total, int nb) {
    __shared__ int sh[1024];
    const int t = threadIdx.x;
    int v = (t < nb) ? blockSums[t] : 0;
    sh[t] = v;
    __syncthreads();
    for (int off = 1; off < 1024; off <<= 1) {
        int add = (t >= off) ? sh[t - off] : 0;
        __syncthreads();
        sh[t] += add;
        __syncthreads();
    }
    if (t < nb) blockSums[t] = sh[t] - v;         // exclusive
    if (t == 1023) *total = sh[1023];             // offs[n]
}

__global__ __launch_bounds__(SCAN_BLK) void scan_add(
    int* __restrict__ offs, int* __restrict__ cursor,
    const int* __restrict__ blockSums, int n) {
    const int i = blockIdx.x * SCAN_BLK + threadIdx.x;
    if (i < n) {
        int o = offs[i] + blockSums[blockIdx.x];
        offs[i]   = o;
        cursor[i] = o;
    }
}

// Fallback single-block scan (only if grid would exceed 1024 blocks).
__global__ __launch_bounds__(SCAN_THREADS) void scan_counts(
    const int* __restrict__ counts, int* __restrict__ offs,
    int* __restrict__ cursor, int n) {
    __shared__ int part[SCAN_THREADS];
    const int t = threadIdx.x;
    const int chunk = (n + SCAN_THREADS - 1) / SCAN_THREADS;
    const int s = t * chunk;
    const int e = min(s + chunk, n);
    int sum = 0;
    for (int i = s; i < e; ++i) sum += counts[i];
    part[t] = sum;
    __syncthreads();
    for (int off = 1; off < SCAN_THREADS; off <<= 1) {
        int add = (t >= off) ? part[t - off] : 0;
        __syncthreads();
        part[t] += add;
        __syncthreads();
    }
    int run = part[t] - sum;
    for (int i = s; i < e; ++i) {
        offs[i]   = run;
        cursor[i] = run;
        run += counts[i];
    }
    if (e == n) offs[n] = run;
}

// One index-atomic per edge; write {col,val} record in destination order.
__global__ void permute_edges(const int* __restrict__ rows,
                              const int* __restrict__ cols,
                              const float* __restrict__ vals,
                              int* __restrict__ cursor, int2* __restrict__ evec,
                              int n_edges) {
    int i = blockIdx.x * blockDim.x + threadIdx.x;
    if (i >= n_edges) return;
    int r   = rows[i];
    int pos = atomicAdd(&cursor[r], 1);
    evec[pos] = make_int2(cols[i], __float_as_int(vals[i]));
}

// ---------------------------------------------------------------- aggregate
// One wave (64 lanes) per node; lane owns float2 of the output row.
__global__ __launch_bounds__(256) void aggregate(
    const int* __restrict__ offs, const int2* __restrict__ evec,
    const float* __restrict__ h, float* __restrict__ out, int n_nodes) {
    int wid = blockIdx.x * (blockDim.x >> 6) + (threadIdx.x >> 6);
    if (wid >= n_nodes) return;
    int lane = threadIdx.x & 63;

    int s = offs[wid];
    int e = offs[wid + 1];
    float2 acc = make_float2(0.f, 0.f);

    int k = s;
    for (; k + 1 < e; k += 2) {
        int2 e0 = evec[k];
        int2 e1 = evec[k + 1];
        float2 h0 = *(const float2*)&h[(size_t)e0.x * D + lane * 2];
        float2 h1 = *(const float2*)&h[(size_t)e1.x * D + lane * 2];
        float v0 = __int_as_float(e0.y);
        float v1 = __int_as_float(e1.y);
        acc.x += v0 * h0.x; acc.y += v0 * h0.y;
        acc.x += v1 * h1.x; acc.y += v1 * h1.y;
    }
    if (k < e) {
        int2 e0 = evec[k];
        float2 h0 = *(const float2*)&h[(size_t)e0.x * D + lane * 2];
        float v0 = __int_as_float(e0.y);
        acc.x += v0 * h0.x; acc.y += v0 * h0.y;
    }

    *(float2*)&out[(size_t)wid * D + lane * 2] = acc;
}

// ---------------------------------------------------------------- fallback
__global__ __launch_bounds__(256) void scatter_add(
    const int* __restrict__ rows, const int* __restrict__ cols,
    const float* __restrict__ vals, const float* __restrict__ h,
    float* __restrict__ out, int n_edges) {
    long long gid = (long long)blockIdx.x * blockDim.x + threadIdx.x;
    int e  = (int)(gid >> 5);
    if (e >= n_edges) return;
    int d4 = ((int)gid & 31) * 4;
    int   r = rows[e];
    int   c = cols[e];
    float v = vals[e];
    float4 hv = *(const float4*)&h[c * D + d4];
    float* op = &out[r * D + d4];
    atomicAdd(op + 0, v * hv.x);
    atomicAdd(op + 1, v * hv.y);
    atomicAdd(op + 2, v * hv.z);
    atomicAdd(op + 3, v * hv.w);
}

// ---------------------------------------------------------------- launch
static inline size_t align16(size_t x) { return (x + 15) & ~(size_t)15; }

extern "C" void kernel_launch(void* const* d_in, const int* in_sizes, int n_in,
                              void* d_out, int out_size, void* d_ws, size_t ws_size,
                              hipStream_t stream) {
    const float* x    = (const float*)d_in[0];
    const int*   rows = (const int*)  d_in[1];
    const int*   cols = (const int*)  d_in[2];
    const float* vals = (const float*)d_in[3];
    const float* W    = (const float*)d_in[4];
    const float* b    = (const float*)d_in[5];
    float*       out  = (float*)d_out;

    const int n_nodes = in_sizes[0] / D;   // 50000
    const int n_edges = in_sizes[1];       // 800000
    const int nScanBlocks = (n_nodes + SCAN_BLK - 1) / SCAN_BLK;   // 196

    // ---- workspace layout (16B-aligned regions)
    char*  base    = (char*)d_ws;
    size_t off     = 0;
    float* Wt      = (float*)(base + off); off = align16(off + (size_t)D * D * 4);
    float* h       = (float*)(base + off); off = align16(off + (size_t)n_nodes * D * 4);
    int*   counts  = (int*)  (base + off); off = align16(off + (size_t)n_nodes * 4);
    int*   offs    = (int*)  (base + off); off = align16(off + ((size_t)n_nodes + 1) * 4);
    int*   cursor  = (int*)  (base + off); off = align16(off + (size_t)n_nodes * 4);
    int*   bsums   = (int*)  (base + off); off = align16(off + (size_t)1024 * 4);
    int2*  evec    = (int2*) (base + off); off = align16(off + (size_t)n_edges * 8);
    const bool csr_fits = (off <= ws_size);

    transpose_W<<<(D * D + 255) / 256, 256, 0, stream>>>(W, Wt);
    gemm_xWt<<<(n_nodes + 31) / 32, 256, 0, stream>>>(x, Wt, b, h, n_nodes);

    if (csr_fits) {
        hipMemsetAsync(counts, 0, (size_t)n_nodes * 4, stream);
        hist_rows<<<(n_edges + 255) / 256, 256, 0, stream>>>(rows, counts, n_edges);
        if (nScanBlocks <= 1024) {
            scan_local<<<nScanBlocks, SCAN_BLK, 0, stream>>>(counts, offs, bsums, n_nodes);
            scan_blocks<<<1, 1024, 0, stream>>>(bsums, &offs[n_nodes], nScanBlocks);
            scan_add<<<nScanBlocks, SCAN_BLK, 0, stream>>>(offs, cursor, bsums, n_nodes);
        } else {
            scan_counts<<<1, SCAN_THREADS, 0, stream>>>(counts, offs, cursor, n_nodes);
        }
        permute_edges<<<(n_edges + 255) / 256, 256, 0, stream>>>(
            rows, cols, vals, cursor, evec, n_edges);
        aggregate<<<(n_nodes + 3) / 4, 256, 0, stream>>>(offs, evec, h, out, n_nodes);
    } else {
        hipMemsetAsync(d_out, 0, (size_t)n_nodes * D * sizeof(float), stream);
        long long scatter_threads = (long long)n_edges * 32;
        int scatter_blocks = (int)((scatter_threads + 255) / 256);
        scatter_add<<<scatter_blocks, 256, 0, stream>>>(rows, cols, vals, h, out, n_edges);
    }
}

// Round 6
// 184.647 us; speedup vs baseline: 7.6653x; 1.2447x over previous
//
#include <hip/hip_runtime.h>

#define D 128
#define SCAN_BLK 256
#define SCAN_THREADS 1024

typedef short  bf16x8 __attribute__((ext_vector_type(8)));
typedef float  f32x4  __attribute__((ext_vector_type(4)));

// round-to-nearest-even float -> bf16 bits
static __device__ __forceinline__ unsigned short f2bf(float f) {
    unsigned u = __float_as_uint(f);
    u += 0x7FFFu + ((u >> 16) & 1u);
    return (unsigned short)(u >> 16);
}
static __device__ __forceinline__ float bf2f_lo(unsigned u) {
    return __uint_as_float((u & 0xFFFFu) << 16);
}
static __device__ __forceinline__ float bf2f_hi(unsigned u) {
    return __uint_as_float(u & 0xFFFF0000u);
}

// ---------------------------------------------------------------- W -> bf16
__global__ void convert_W(const float* __restrict__ W, unsigned short* __restrict__ Wb) {
    int i = blockIdx.x * blockDim.x + threadIdx.x;   // 0 .. D*D-1
    if (i < D * D) Wb[i] = f2bf(W[i]);
}

// ---------------------------------------------------------------- MFMA GEMM
// h[m][o] = sum_k x[m][k] * W[o][k] + b[o], stored as bf16.
// Block = 256 thr = 4 waves; wave w owns rows row0..row0+15, all 128 cols.
// A-frag: x[row0+(lane&15)][ks*32 + (lane>>4)*8 ..+7]   (fp32 load, cvt in-reg)
// B-frag: Wb[(n*16+(lane&15))*128 + ks*32 + (lane>>4)*8] (16B load, L1/L2-hot)
// C/D:    col = lane&15, row = (lane>>4)*4 + j          (m89-verified layout)
__global__ __launch_bounds__(256) void gemm_mfma(
    const float* __restrict__ x, const unsigned short* __restrict__ Wb,
    const float* __restrict__ b, unsigned short* __restrict__ hb, int n_rows) {
    const int lane = threadIdx.x & 63;
    const int wv   = threadIdx.x >> 6;
    const int row0 = blockIdx.x * 64 + wv * 16;
    if (row0 >= n_rows) return;               // whole-wave exit; no __syncthreads used
    const int m  = lane & 15;
    const int kg = lane >> 4;                 // 0..3

    int arow = row0 + m;
    if (arow >= n_rows) arow = n_rows - 1;    // clamp: loads valid, stores predicated
    const float* xr = x + (size_t)arow * D + kg * 8;

    f32x4 acc[8];
#pragma unroll
    for (int n = 0; n < 8; ++n) acc[n] = (f32x4){0.f, 0.f, 0.f, 0.f};

#pragma unroll
    for (int ks = 0; ks < 4; ++ks) {
        float4 f0 = *(const float4*)(xr + ks * 32);
        float4 f1 = *(const float4*)(xr + ks * 32 + 4);
        bf16x8 a;
        a[0] = (short)f2bf(f0.x); a[1] = (short)f2bf(f0.y);
        a[2] = (short)f2bf(f0.z); a[3] = (short)f2bf(f0.w);
        a[4] = (short)f2bf(f1.x); a[5] = (short)f2bf(f1.y);
        a[6] = (short)f2bf(f1.z); a[7] = (short)f2bf(f1.w);
#pragma unroll
        for (int n = 0; n < 8; ++n) {
            bf16x8 bf = *(const bf16x8*)&Wb[(size_t)(n * 16 + m) * D + ks * 32 + kg * 8];
            acc[n] = __builtin_amdgcn_mfma_f32_16x16x32_bf16(a, bf, acc[n], 0, 0, 0);
        }
    }

#pragma unroll
    for (int n = 0; n < 8; ++n) {
        int col = n * 16 + m;
        float bc = b[col];
#pragma unroll
        for (int j = 0; j < 4; ++j) {
            int r = row0 + kg * 4 + j;
            if (r < n_rows) hb[(size_t)r * D + col] = f2bf(acc[n][j] + bc);
        }
    }
}

// ---------------------------------------------------------------- CSR build
__global__ void hist_rows(const int* __restrict__ rows, int* __restrict__ counts,
                          int n_edges) {
    int i = blockIdx.x * blockDim.x + threadIdx.x;
    if (i < n_edges) atomicAdd(&counts[rows[i]], 1);
}

__global__ __launch_bounds__(SCAN_BLK) void scan_local(
    const int* __restrict__ counts, int* __restrict__ offs,
    int* __restrict__ blockSums, int n) {
    __shared__ int sh[SCAN_BLK];
    const int t = threadIdx.x;
    const int i = blockIdx.x * SCAN_BLK + t;
    int v = (i < n) ? counts[i] : 0;
    sh[t] = v;
    __syncthreads();
    for (int off = 1; off < SCAN_BLK; off <<= 1) {
        int add = (t >= off) ? sh[t - off] : 0;
        __syncthreads();
        sh[t] += add;
        __syncthreads();
    }
    if (i < n) offs[i] = sh[t] - v;
    if (t == SCAN_BLK - 1) blockSums[blockIdx.x] = sh[SCAN_BLK - 1];
}

__global__ __launch_bounds__(1024) void scan_blocks(
    int* __restrict__ blockSums, int* __restrict__ total, int nb) {
    __shared__ int sh[1024];
    const int t = threadIdx.x;
    int v = (t < nb) ? blockSums[t] : 0;
    sh[t] = v;
    __syncthreads();
    for (int off = 1; off < 1024; off <<= 1) {
        int add = (t >= off) ? sh[t - off] : 0;
        __syncthreads();
        sh[t] += add;
        __syncthreads();
    }
    if (t < nb) blockSums[t] = sh[t] - v;
    if (t == 1023) *total = sh[1023];
}

__global__ __launch_bounds__(SCAN_BLK) void scan_add(
    int* __restrict__ offs, int* __restrict__ cursor,
    const int* __restrict__ blockSums, int n) {
    const int i = blockIdx.x * SCAN_BLK + threadIdx.x;
    if (i < n) {
        int o = offs[i] + blockSums[blockIdx.x];
        offs[i]   = o;
        cursor[i] = o;
    }
}

__global__ __launch_bounds__(SCAN_THREADS) void scan_counts(
    const int* __restrict__ counts, int* __restrict__ offs,
    int* __restrict__ cursor, int n) {
    __shared__ int part[SCAN_THREADS];
    const int t = threadIdx.x;
    const int chunk = (n + SCAN_THREADS - 1) / SCAN_THREADS;
    const int s = t * chunk;
    const int e = min(s + chunk, n);
    int sum = 0;
    for (int i = s; i < e; ++i) sum += counts[i];
    part[t] = sum;
    __syncthreads();
    for (int off = 1; off < SCAN_THREADS; off <<= 1) {
        int add = (t >= off) ? part[t - off] : 0;
        __syncthreads();
        part[t] += add;
        __syncthreads();
    }
    int run = part[t] - sum;
    for (int i = s; i < e; ++i) {
        offs[i]   = run;
        cursor[i] = run;
        run += counts[i];
    }
    if (e == n) offs[n] = run;
}

__global__ void permute_edges(const int* __restrict__ rows,
                              const int* __restrict__ cols,
                              const float* __restrict__ vals,
                              int* __restrict__ cursor, int2* __restrict__ evec,
                              int n_edges) {
    int i = blockIdx.x * blockDim.x + threadIdx.x;
    if (i >= n_edges) return;
    int r   = rows[i];
    int pos = atomicAdd(&cursor[r], 1);
    evec[pos] = make_int2(cols[i], __float_as_int(vals[i]));
}

// ---------------------------------------------------------------- aggregate
// One wave per node; lane owns 2 cols. Gather = 4 B/lane (256 B/edge, bf16 h).
__global__ __launch_bounds__(256) void aggregate(
    const int* __restrict__ offs, const int2* __restrict__ evec,
    const unsigned short* __restrict__ hb, float* __restrict__ out, int n_nodes) {
    int wid = blockIdx.x * (blockDim.x >> 6) + (threadIdx.x >> 6);
    if (wid >= n_nodes) return;
    int lane = threadIdx.x & 63;

    int s = offs[wid];
    int e = offs[wid + 1];
    float2 acc = make_float2(0.f, 0.f);

    int k = s;
    for (; k + 1 < e; k += 2) {
        int2 e0 = evec[k];
        int2 e1 = evec[k + 1];
        unsigned u0 = *(const unsigned*)&hb[(size_t)e0.x * D + lane * 2];
        unsigned u1 = *(const unsigned*)&hb[(size_t)e1.x * D + lane * 2];
        float v0 = __int_as_float(e0.y);
        float v1 = __int_as_float(e1.y);
        acc.x += v0 * bf2f_lo(u0); acc.y += v0 * bf2f_hi(u0);
        acc.x += v1 * bf2f_lo(u1); acc.y += v1 * bf2f_hi(u1);
    }
    if (k < e) {
        int2 e0 = evec[k];
        unsigned u0 = *(const unsigned*)&hb[(size_t)e0.x * D + lane * 2];
        float v0 = __int_as_float(e0.y);
        acc.x += v0 * bf2f_lo(u0); acc.y += v0 * bf2f_hi(u0);
    }

    *(float2*)&out[(size_t)wid * D + lane * 2] = acc;
}

// ---------------------------------------------------------------- fallback
__global__ __launch_bounds__(256) void scatter_add(
    const int* __restrict__ rows, const int* __restrict__ cols,
    const float* __restrict__ vals, const unsigned short* __restrict__ hb,
    float* __restrict__ out, int n_edges) {
    long long gid = (long long)blockIdx.x * blockDim.x + threadIdx.x;
    int e  = (int)(gid >> 5);
    if (e >= n_edges) return;
    int d4 = ((int)gid & 31) * 4;
    int   r = rows[e];
    int   c = cols[e];
    float v = vals[e];
    const unsigned short* hp = &hb[(size_t)c * D + d4];
    unsigned u0 = *(const unsigned*)(hp + 0);
    unsigned u1 = *(const unsigned*)(hp + 2);
    float* op = &out[(size_t)r * D + d4];
    atomicAdd(op + 0, v * bf2f_lo(u0));
    atomicAdd(op + 1, v * bf2f_hi(u0));
    atomicAdd(op + 2, v * bf2f_lo(u1));
    atomicAdd(op + 3, v * bf2f_hi(u1));
}

// ---------------------------------------------------------------- launch
static inline size_t align16(size_t x) { return (x + 15) & ~(size_t)15; }

extern "C" void kernel_launch(void* const* d_in, const int* in_sizes, int n_in,
                              void* d_out, int out_size, void* d_ws, size_t ws_size,
                              hipStream_t stream) {
    const float* x    = (const float*)d_in[0];
    const int*   rows = (const int*)  d_in[1];
    const int*   cols = (const int*)  d_in[2];
    const float* vals = (const float*)d_in[3];
    const float* W    = (const float*)d_in[4];
    const float* b    = (const float*)d_in[5];
    float*       out  = (float*)d_out;

    const int n_nodes = in_sizes[0] / D;   // 50000
    const int n_edges = in_sizes[1];       // 800000
    const int nScanBlocks = (n_nodes + SCAN_BLK - 1) / SCAN_BLK;

    // ---- workspace layout (16B-aligned regions)
    char*  base    = (char*)d_ws;
    size_t off     = 0;
    unsigned short* Wb = (unsigned short*)(base + off); off = align16(off + (size_t)D * D * 2);
    unsigned short* hb = (unsigned short*)(base + off); off = align16(off + (size_t)n_nodes * D * 2);
    int*   counts  = (int*)  (base + off); off = align16(off + (size_t)n_nodes * 4);
    int*   offs    = (int*)  (base + off); off = align16(off + ((size_t)n_nodes + 1) * 4);
    int*   cursor  = (int*)  (base + off); off = align16(off + (size_t)n_nodes * 4);
    int*   bsums   = (int*)  (base + off); off = align16(off + (size_t)1024 * 4);
    int2*  evec    = (int2*) (base + off); off = align16(off + (size_t)n_edges * 8);
    const bool csr_fits = (off <= ws_size);

    convert_W<<<(D * D + 255) / 256, 256, 0, stream>>>(W, Wb);
    gemm_mfma<<<(n_nodes + 63) / 64, 256, 0, stream>>>(x, Wb, b, hb, n_nodes);

    if (csr_fits) {
        hipMemsetAsync(counts, 0, (size_t)n_nodes * 4, stream);
        hist_rows<<<(n_edges + 255) / 256, 256, 0, stream>>>(rows, counts, n_edges);
        if (nScanBlocks <= 1024) {
            scan_local<<<nScanBlocks, SCAN_BLK, 0, stream>>>(counts, offs, bsums, n_nodes);
            scan_blocks<<<1, 1024, 0, stream>>>(bsums, &offs[n_nodes], nScanBlocks);
            scan_add<<<nScanBlocks, SCAN_BLK, 0, stream>>>(offs, cursor, bsums, n_nodes);
        } else {
            scan_counts<<<1, SCAN_THREADS, 0, stream>>>(counts, offs, cursor, n_nodes);
        }
        permute_edges<<<(n_edges + 255) / 256, 256, 0, stream>>>(
            rows, cols, vals, cursor, evec, n_edges);
        aggregate<<<(n_nodes + 3) / 4, 256, 0, stream>>>(offs, evec, hb, out, n_nodes);
    } else {
        hipMemsetAsync(d_out, 0, (size_t)n_nodes * D * sizeof(float), stream);
        long long scatter_threads = (long long)n_edges * 32;
        int scatter_blocks = (int)((scatter_threads + 255) / 256);
        scatter_add<<<scatter_blocks, 256, 0, stream>>>(rows, cols, vals, hb, out, n_edges);
    }
}

// Round 7
// 175.111 us; speedup vs baseline: 8.0827x; 1.0545x over previous
//
#include <hip/hip_runtime.h>

#define D 128
#define SCAN_BLK 256
#define SCAN_THREADS 1024

typedef short  bf16x8 __attribute__((ext_vector_type(8)));
typedef float  f32x4  __attribute__((ext_vector_type(4)));

// round-to-nearest-even float -> bf16 bits
static __device__ __forceinline__ unsigned short f2bf(float f) {
    unsigned u = __float_as_uint(f);
    u += 0x7FFFu + ((u >> 16) & 1u);
    return (unsigned short)(u >> 16);
}
static __device__ __forceinline__ float bf2f_lo(unsigned u) {
    return __uint_as_float((u & 0xFFFFu) << 16);
}
static __device__ __forceinline__ float bf2f_hi(unsigned u) {
    return __uint_as_float(u & 0xFFFF0000u);
}

// ------------------------------------------------ fused: hist_rows + convert_W
// hist blocks first (big), convert blocks after (64). Independent work.
__global__ __launch_bounds__(256) void fused_pre(
    const int* __restrict__ rows, int* __restrict__ counts, int n_edges,
    const float* __restrict__ W, unsigned short* __restrict__ Wb, int histBlocks) {
    int bid = blockIdx.x;
    if (bid < histBlocks) {
        int i = bid * 256 + threadIdx.x;
        if (i < n_edges) atomicAdd(&counts[rows[i]], 1);
    } else {
        int i = (bid - histBlocks) * 256 + threadIdx.x;
        if (i < D * D) Wb[i] = f2bf(W[i]);
    }
}

// ------------------------------------------------ fused: permute + MFMA GEMM
// Permute blocks FIRST (longer pole; write-pipe-bound, VALU idle),
// gemm blocks after (MFMA + read-BW). No mutual dependency.
__global__ __launch_bounds__(256) void fused_main(
    // permute args
    const int* __restrict__ rows, const int* __restrict__ cols,
    const float* __restrict__ vals, int* __restrict__ cursor,
    int2* __restrict__ evec, int n_edges, int permBlocks,
    // gemm args
    const float* __restrict__ x, const unsigned short* __restrict__ Wb,
    const float* __restrict__ b, unsigned short* __restrict__ hb, int n_rows) {
    int bid = blockIdx.x;
    if (bid < permBlocks) {
        int i = bid * 256 + threadIdx.x;
        if (i >= n_edges) return;
        int r   = rows[i];
        int pos = atomicAdd(&cursor[r], 1);
        evec[pos] = make_int2(cols[i], __float_as_int(vals[i]));
        return;
    }

    // ---- gemm part: h[m][o] = sum_k x[m][k]*W[o][k] + b[o] -> bf16
    const int gb   = bid - permBlocks;
    const int lane = threadIdx.x & 63;
    const int wv   = threadIdx.x >> 6;
    const int row0 = gb * 64 + wv * 16;
    if (row0 >= n_rows) return;
    const int m  = lane & 15;
    const int kg = lane >> 4;                 // 0..3

    int arow = row0 + m;
    if (arow >= n_rows) arow = n_rows - 1;    // clamp: loads valid, stores predicated
    const float* xr = x + (size_t)arow * D + kg * 8;

    f32x4 acc[8];
#pragma unroll
    for (int n = 0; n < 8; ++n) acc[n] = (f32x4){0.f, 0.f, 0.f, 0.f};

#pragma unroll
    for (int ks = 0; ks < 4; ++ks) {
        float4 f0 = *(const float4*)(xr + ks * 32);
        float4 f1 = *(const float4*)(xr + ks * 32 + 4);
        bf16x8 a;
        a[0] = (short)f2bf(f0.x); a[1] = (short)f2bf(f0.y);
        a[2] = (short)f2bf(f0.z); a[3] = (short)f2bf(f0.w);
        a[4] = (short)f2bf(f1.x); a[5] = (short)f2bf(f1.y);
        a[6] = (short)f2bf(f1.z); a[7] = (short)f2bf(f1.w);
#pragma unroll
        for (int n = 0; n < 8; ++n) {
            bf16x8 bf = *(const bf16x8*)&Wb[(size_t)(n * 16 + m) * D + ks * 32 + kg * 8];
            acc[n] = __builtin_amdgcn_mfma_f32_16x16x32_bf16(a, bf, acc[n], 0, 0, 0);
        }
    }

#pragma unroll
    for (int n = 0; n < 8; ++n) {
        int col = n * 16 + m;
        float bc = b[col];
#pragma unroll
        for (int j = 0; j < 4; ++j) {
            int r = row0 + kg * 4 + j;
            if (r < n_rows) hb[(size_t)r * D + col] = f2bf(acc[n][j] + bc);
        }
    }
}

// ---------------------------------------------------------------- scan chain
__global__ __launch_bounds__(SCAN_BLK) void scan_local(
    const int* __restrict__ counts, int* __restrict__ offs,
    int* __restrict__ blockSums, int n) {
    __shared__ int sh[SCAN_BLK];
    const int t = threadIdx.x;
    const int i = blockIdx.x * SCAN_BLK + t;
    int v = (i < n) ? counts[i] : 0;
    sh[t] = v;
    __syncthreads();
    for (int off = 1; off < SCAN_BLK; off <<= 1) {
        int add = (t >= off) ? sh[t - off] : 0;
        __syncthreads();
        sh[t] += add;
        __syncthreads();
    }
    if (i < n) offs[i] = sh[t] - v;
    if (t == SCAN_BLK - 1) blockSums[blockIdx.x] = sh[SCAN_BLK - 1];
}

__global__ __launch_bounds__(1024) void scan_blocks(
    int* __restrict__ blockSums, int* __restrict__ total, int nb) {
    __shared__ int sh[1024];
    const int t = threadIdx.x;
    int v = (t < nb) ? blockSums[t] : 0;
    sh[t] = v;
    __syncthreads();
    for (int off = 1; off < 1024; off <<= 1) {
        int add = (t >= off) ? sh[t - off] : 0;
        __syncthreads();
        sh[t] += add;
        __syncthreads();
    }
    if (t < nb) blockSums[t] = sh[t] - v;
    if (t == 1023) *total = sh[1023];
}

__global__ __launch_bounds__(SCAN_BLK) void scan_add(
    int* __restrict__ offs, int* __restrict__ cursor,
    const int* __restrict__ blockSums, int n) {
    const int i = blockIdx.x * SCAN_BLK + threadIdx.x;
    if (i < n) {
        int o = offs[i] + blockSums[blockIdx.x];
        offs[i]   = o;
        cursor[i] = o;
    }
}

__global__ __launch_bounds__(SCAN_THREADS) void scan_counts(
    const int* __restrict__ counts, int* __restrict__ offs,
    int* __restrict__ cursor, int n) {
    __shared__ int part[SCAN_THREADS];
    const int t = threadIdx.x;
    const int chunk = (n + SCAN_THREADS - 1) / SCAN_THREADS;
    const int s = t * chunk;
    const int e = min(s + chunk, n);
    int sum = 0;
    for (int i = s; i < e; ++i) sum += counts[i];
    part[t] = sum;
    __syncthreads();
    for (int off = 1; off < SCAN_THREADS; off <<= 1) {
        int add = (t >= off) ? part[t - off] : 0;
        __syncthreads();
        part[t] += add;
        __syncthreads();
    }
    int run = part[t] - sum;
    for (int i = s; i < e; ++i) {
        offs[i]   = run;
        cursor[i] = run;
        run += counts[i];
    }
    if (e == n) offs[n] = run;
}

// ---------------------------------------------------------------- aggregate
// One wave per node; lane owns 2 cols (4 B of bf16 h per gather).
// 4 records per iteration: 2x int4 broadcast loads of evec + 4 gathers in
// flight -> deeper MLP than the old 2-wide loop (was latency-bound, VALUBusy 27%).
__global__ __launch_bounds__(256) void aggregate(
    const int* __restrict__ offs, const int2* __restrict__ evec,
    const unsigned short* __restrict__ hb, float* __restrict__ out, int n_nodes) {
    int wid = blockIdx.x * (blockDim.x >> 6) + (threadIdx.x >> 6);
    if (wid >= n_nodes) return;
    int lane = threadIdx.x & 63;

    int s = offs[wid];
    int e = offs[wid + 1];
    float2 acc = make_float2(0.f, 0.f);

    int k = s;
    // peel to even k so int4 loads are 16B-aligned
    if ((k & 1) && k < e) {
        int2 e0 = evec[k];
        unsigned u0 = *(const unsigned*)&hb[(size_t)e0.x * D + lane * 2];
        float v0 = __int_as_float(e0.y);
        acc.x += v0 * bf2f_lo(u0); acc.y += v0 * bf2f_hi(u0);
        ++k;
    }
    for (; k + 3 < e; k += 4) {
        int4 p0 = *(const int4*)&evec[k];       // records k, k+1
        int4 p1 = *(const int4*)&evec[k + 2];   // records k+2, k+3
        unsigned u0 = *(const unsigned*)&hb[(size_t)p0.x * D + lane * 2];
        unsigned u1 = *(const unsigned*)&hb[(size_t)p0.z * D + lane * 2];
        unsigned u2 = *(const unsigned*)&hb[(size_t)p1.x * D + lane * 2];
        unsigned u3 = *(const unsigned*)&hb[(size_t)p1.z * D + lane * 2];
        float v0 = __int_as_float(p0.y);
        float v1 = __int_as_float(p0.w);
        float v2 = __int_as_float(p1.y);
        float v3 = __int_as_float(p1.w);
        acc.x += v0 * bf2f_lo(u0); acc.y += v0 * bf2f_hi(u0);
        acc.x += v1 * bf2f_lo(u1); acc.y += v1 * bf2f_hi(u1);
        acc.x += v2 * bf2f_lo(u2); acc.y += v2 * bf2f_hi(u2);
        acc.x += v3 * bf2f_lo(u3); acc.y += v3 * bf2f_hi(u3);
    }
    for (; k < e; ++k) {
        int2 e0 = evec[k];
        unsigned u0 = *(const unsigned*)&hb[(size_t)e0.x * D + lane * 2];
        float v0 = __int_as_float(e0.y);
        acc.x += v0 * bf2f_lo(u0); acc.y += v0 * bf2f_hi(u0);
    }

    *(float2*)&out[(size_t)wid * D + lane * 2] = acc;
}

// ---------------------------------------------------------------- fallback
__global__ __launch_bounds__(256) void scatter_add(
    const int* __restrict__ rows, const int* __restrict__ cols,
    const float* __restrict__ vals, const unsigned short* __restrict__ hb,
    float* __restrict__ out, int n_edges) {
    long long gid = (long long)blockIdx.x * blockDim.x + threadIdx.x;
    int e  = (int)(gid >> 5);
    if (e >= n_edges) return;
    int d4 = ((int)gid & 31) * 4;
    int   r = rows[e];
    int   c = cols[e];
    float v = vals[e];
    const unsigned short* hp = &hb[(size_t)c * D + d4];
    unsigned u0 = *(const unsigned*)(hp + 0);
    unsigned u1 = *(const unsigned*)(hp + 2);
    float* op = &out[(size_t)r * D + d4];
    atomicAdd(op + 0, v * bf2f_lo(u0));
    atomicAdd(op + 1, v * bf2f_hi(u0));
    atomicAdd(op + 2, v * bf2f_lo(u1));
    atomicAdd(op + 3, v * bf2f_hi(u1));
}

__global__ void convert_W(const float* __restrict__ W, unsigned short* __restrict__ Wb) {
    int i = blockIdx.x * blockDim.x + threadIdx.x;
    if (i < D * D) Wb[i] = f2bf(W[i]);
}

__global__ __launch_bounds__(256) void gemm_mfma(
    const float* __restrict__ x, const unsigned short* __restrict__ Wb,
    const float* __restrict__ b, unsigned short* __restrict__ hb, int n_rows) {
    const int lane = threadIdx.x & 63;
    const int wv   = threadIdx.x >> 6;
    const int row0 = blockIdx.x * 64 + wv * 16;
    if (row0 >= n_rows) return;
    const int m  = lane & 15;
    const int kg = lane >> 4;
    int arow = row0 + m;
    if (arow >= n_rows) arow = n_rows - 1;
    const float* xr = x + (size_t)arow * D + kg * 8;
    f32x4 acc[8];
#pragma unroll
    for (int n = 0; n < 8; ++n) acc[n] = (f32x4){0.f, 0.f, 0.f, 0.f};
#pragma unroll
    for (int ks = 0; ks < 4; ++ks) {
        float4 f0 = *(const float4*)(xr + ks * 32);
        float4 f1 = *(const float4*)(xr + ks * 32 + 4);
        bf16x8 a;
        a[0] = (short)f2bf(f0.x); a[1] = (short)f2bf(f0.y);
        a[2] = (short)f2bf(f0.z); a[3] = (short)f2bf(f0.w);
        a[4] = (short)f2bf(f1.x); a[5] = (short)f2bf(f1.y);
        a[6] = (short)f2bf(f1.z); a[7] = (short)f2bf(f1.w);
#pragma unroll
        for (int n = 0; n < 8; ++n) {
            bf16x8 bf = *(const bf16x8*)&Wb[(size_t)(n * 16 + m) * D + ks * 32 + kg * 8];
            acc[n] = __builtin_amdgcn_mfma_f32_16x16x32_bf16(a, bf, acc[n], 0, 0, 0);
        }
    }
#pragma unroll
    for (int n = 0; n < 8; ++n) {
        int col = n * 16 + m;
        float bc = b[col];
#pragma unroll
        for (int j = 0; j < 4; ++j) {
            int r = row0 + kg * 4 + j;
            if (r < n_rows) hb[(size_t)r * D + col] = f2bf(acc[n][j] + bc);
        }
    }
}

// ---------------------------------------------------------------- launch
static inline size_t align16(size_t x) { return (x + 15) & ~(size_t)15; }

extern "C" void kernel_launch(void* const* d_in, const int* in_sizes, int n_in,
                              void* d_out, int out_size, void* d_ws, size_t ws_size,
                              hipStream_t stream) {
    const float* x    = (const float*)d_in[0];
    const int*   rows = (const int*)  d_in[1];
    const int*   cols = (const int*)  d_in[2];
    const float* vals = (const float*)d_in[3];
    const float* W    = (const float*)d_in[4];
    const float* b    = (const float*)d_in[5];
    float*       out  = (float*)d_out;

    const int n_nodes = in_sizes[0] / D;   // 50000
    const int n_edges = in_sizes[1];       // 800000
    const int nScanBlocks = (n_nodes + SCAN_BLK - 1) / SCAN_BLK;
    const int histBlocks  = (n_edges + 255) / 256;
    const int convBlocks  = (D * D + 255) / 256;
    const int gemmBlocks  = (n_nodes + 63) / 64;

    // ---- workspace layout (16B-aligned regions)
    char*  base    = (char*)d_ws;
    size_t off     = 0;
    unsigned short* Wb = (unsigned short*)(base + off); off = align16(off + (size_t)D * D * 2);
    unsigned short* hb = (unsigned short*)(base + off); off = align16(off + (size_t)n_nodes * D * 2);
    int*   counts  = (int*)  (base + off); off = align16(off + (size_t)n_nodes * 4);
    int*   offs    = (int*)  (base + off); off = align16(off + ((size_t)n_nodes + 1) * 4);
    int*   cursor  = (int*)  (base + off); off = align16(off + (size_t)n_nodes * 4);
    int*   bsums   = (int*)  (base + off); off = align16(off + (size_t)1024 * 4);
    int2*  evec    = (int2*) (base + off); off = align16(off + (size_t)n_edges * 8);
    const bool csr_fits = (off <= ws_size);

    if (csr_fits) {
        hipMemsetAsync(counts, 0, (size_t)n_nodes * 4, stream);
        fused_pre<<<histBlocks + convBlocks, 256, 0, stream>>>(
            rows, counts, n_edges, W, Wb, histBlocks);
        if (nScanBlocks <= 1024) {
            scan_local<<<nScanBlocks, SCAN_BLK, 0, stream>>>(counts, offs, bsums, n_nodes);
            scan_blocks<<<1, 1024, 0, stream>>>(bsums, &offs[n_nodes], nScanBlocks);
            scan_add<<<nScanBlocks, SCAN_BLK, 0, stream>>>(offs, cursor, bsums, n_nodes);
        } else {
            scan_counts<<<1, SCAN_THREADS, 0, stream>>>(counts, offs, cursor, n_nodes);
        }
        fused_main<<<histBlocks + gemmBlocks, 256, 0, stream>>>(
            rows, cols, vals, cursor, evec, n_edges, histBlocks,
            x, Wb, b, hb, n_nodes);
        aggregate<<<(n_nodes + 3) / 4, 256, 0, stream>>>(offs, evec, hb, out, n_nodes);
    } else {
        convert_W<<<convBlocks, 256, 0, stream>>>(W, Wb);
        gemm_mfma<<<gemmBlocks, 256, 0, stream>>>(x, Wb, b, hb, n_nodes);
        hipMemsetAsync(d_out, 0, (size_t)n_nodes * D * sizeof(float), stream);
        long long scatter_threads = (long long)n_edges * 32;
        int scatter_blocks = (int)((scatter_threads + 255) / 256);
        scatter_add<<<scatter_blocks, 256, 0, stream>>>(rows, cols, vals, hb, out, n_edges);
    }
}

// Round 8
// 141.402 us; speedup vs baseline: 10.0096x; 1.2384x over previous
//
#include <hip/hip_runtime.h>

#define D 128
#define SCAN_BLK 256
#define SCAN_THREADS 1024

typedef short  bf16x8 __attribute__((ext_vector_type(8)));
typedef float  f32x4  __attribute__((ext_vector_type(4)));

// round-to-nearest-even float -> bf16 bits
static __device__ __forceinline__ unsigned short f2bf(float f) {
    unsigned u = __float_as_uint(f);
    u += 0x7FFFu + ((u >> 16) & 1u);
    return (unsigned short)(u >> 16);
}
static __device__ __forceinline__ float bf2f_lo(unsigned u) {
    return __uint_as_float((u & 0xFFFFu) << 16);
}
static __device__ __forceinline__ float bf2f_hi(unsigned u) {
    return __uint_as_float(u & 0xFFFF0000u);
}

// ------------------------------------------------ fused: hist_rows + convert_W
__global__ __launch_bounds__(256) void fused_pre(
    const int* __restrict__ rows, int* __restrict__ counts, int n_edges,
    const float* __restrict__ W, unsigned short* __restrict__ Wb, int histBlocks) {
    int bid = blockIdx.x;
    if (bid < histBlocks) {
        int i = bid * 256 + threadIdx.x;
        if (i < n_edges) atomicAdd(&counts[rows[i]], 1);
    } else {
        int i = (bid - histBlocks) * 256 + threadIdx.x;
        if (i < D * D) Wb[i] = f2bf(W[i]);
    }
}

// ------------------------------------------------ fused: permute + MFMA GEMM
// INTERLEAVED roles: groups of 5 blocks = 2 gemm + 3 grid-stride permute, so
// both populations are co-resident for the whole kernel (R7 lesson: putting
// all permute blocks first made the phases nearly sequential -> no overlap).
__global__ __launch_bounds__(256) void fused_main(
    const int* __restrict__ rows, const int* __restrict__ cols,
    const float* __restrict__ vals, int* __restrict__ cursor,
    int2* __restrict__ evec, int n_edges, int permSlots,
    const float* __restrict__ x, const unsigned short* __restrict__ Wb,
    const float* __restrict__ b, unsigned short* __restrict__ hb, int n_rows) {
    const int bid = blockIdx.x;
    const int g   = bid / 5;
    const int r5  = bid % 5;

    if (r5 >= 2) {
        // ---- permute slot: grid-stride over edges
        const int slot   = g * 3 + (r5 - 2);
        const int stride = permSlots * 256;
        for (int i = slot * 256 + threadIdx.x; i < n_edges; i += stride) {
            int rr  = rows[i];
            int pos = atomicAdd(&cursor[rr], 1);
            evec[pos] = make_int2(cols[i], __float_as_int(vals[i]));
        }
        return;
    }

    // ---- gemm slot: h[m][o] = sum_k x[m][k]*W[o][k] + b[o] -> bf16
    const int gb   = g * 2 + r5;
    const int lane = threadIdx.x & 63;
    const int wv   = threadIdx.x >> 6;
    const int row0 = gb * 64 + wv * 16;
    if (row0 >= n_rows) return;               // no __syncthreads in this path
    const int m  = lane & 15;
    const int kg = lane >> 4;                 // 0..3

    int arow = row0 + m;
    if (arow >= n_rows) arow = n_rows - 1;    // clamp: loads valid, stores predicated
    const float* xr = x + (size_t)arow * D + kg * 8;

    f32x4 acc[8];
#pragma unroll
    for (int n = 0; n < 8; ++n) acc[n] = (f32x4){0.f, 0.f, 0.f, 0.f};

#pragma unroll
    for (int ks = 0; ks < 4; ++ks) {
        float4 f0 = *(const float4*)(xr + ks * 32);
        float4 f1 = *(const float4*)(xr + ks * 32 + 4);
        bf16x8 a;
        a[0] = (short)f2bf(f0.x); a[1] = (short)f2bf(f0.y);
        a[2] = (short)f2bf(f0.z); a[3] = (short)f2bf(f0.w);
        a[4] = (short)f2bf(f1.x); a[5] = (short)f2bf(f1.y);
        a[6] = (short)f2bf(f1.z); a[7] = (short)f2bf(f1.w);
#pragma unroll
        for (int n = 0; n < 8; ++n) {
            bf16x8 bf = *(const bf16x8*)&Wb[(size_t)(n * 16 + m) * D + ks * 32 + kg * 8];
            acc[n] = __builtin_amdgcn_mfma_f32_16x16x32_bf16(a, bf, acc[n], 0, 0, 0);
        }
    }

#pragma unroll
    for (int n = 0; n < 8; ++n) {
        int col = n * 16 + m;
        float bc = b[col];
#pragma unroll
        for (int j = 0; j < 4; ++j) {
            int rr = row0 + kg * 4 + j;
            if (rr < n_rows) hb[(size_t)rr * D + col] = f2bf(acc[n][j] + bc);
        }
    }
}

// ---------------------------------------------------------------- scan chain
__global__ __launch_bounds__(SCAN_BLK) void scan_local(
    const int* __restrict__ counts, int* __restrict__ offs,
    int* __restrict__ blockSums, int n) {
    __shared__ int sh[SCAN_BLK];
    const int t = threadIdx.x;
    const int i = blockIdx.x * SCAN_BLK + t;
    int v = (i < n) ? counts[i] : 0;
    sh[t] = v;
    __syncthreads();
    for (int off = 1; off < SCAN_BLK; off <<= 1) {
        int add = (t >= off) ? sh[t - off] : 0;
        __syncthreads();
        sh[t] += add;
        __syncthreads();
    }
    if (i < n) offs[i] = sh[t] - v;
    if (t == SCAN_BLK - 1) blockSums[blockIdx.x] = sh[SCAN_BLK - 1];
}

__global__ __launch_bounds__(1024) void scan_blocks(
    int* __restrict__ blockSums, int* __restrict__ total, int nb) {
    __shared__ int sh[1024];
    const int t = threadIdx.x;
    int v = (t < nb) ? blockSums[t] : 0;
    sh[t] = v;
    __syncthreads();
    for (int off = 1; off < 1024; off <<= 1) {
        int add = (t >= off) ? sh[t - off] : 0;
        __syncthreads();
        sh[t] += add;
        __syncthreads();
    }
    if (t < nb) blockSums[t] = sh[t] - v;
    if (t == 1023) *total = sh[1023];
}

__global__ __launch_bounds__(SCAN_BLK) void scan_add(
    int* __restrict__ offs, int* __restrict__ cursor,
    const int* __restrict__ blockSums, int n) {
    const int i = blockIdx.x * SCAN_BLK + threadIdx.x;
    if (i < n) {
        int o = offs[i] + blockSums[blockIdx.x];
        offs[i]   = o;
        cursor[i] = o;
    }
}

__global__ __launch_bounds__(SCAN_THREADS) void scan_counts(
    const int* __restrict__ counts, int* __restrict__ offs,
    int* __restrict__ cursor, int n) {
    __shared__ int part[SCAN_THREADS];
    const int t = threadIdx.x;
    const int chunk = (n + SCAN_THREADS - 1) / SCAN_THREADS;
    const int s = t * chunk;
    const int e = min(s + chunk, n);
    int sum = 0;
    for (int i = s; i < e; ++i) sum += counts[i];
    part[t] = sum;
    __syncthreads();
    for (int off = 1; off < SCAN_THREADS; off <<= 1) {
        int add = (t >= off) ? part[t - off] : 0;
        __syncthreads();
        part[t] += add;
        __syncthreads();
    }
    int run = part[t] - sum;
    for (int i = s; i < e; ++i) {
        offs[i]   = run;
        cursor[i] = run;
        run += counts[i];
    }
    if (e == n) offs[n] = run;
}

// ---------------------------------------------------------------- aggregate
// One wave per node; lane owns 2 cols (4 B of bf16 h per gather).
// 8 records in flight per iteration (4x int4 broadcast evec loads + 8 gathers)
// to cover ~300-500 cyc L2/L3 gather latency.
__global__ __launch_bounds__(256) void aggregate(
    const int* __restrict__ offs, const int2* __restrict__ evec,
    const unsigned short* __restrict__ hb, float* __restrict__ out, int n_nodes) {
    int wid = blockIdx.x * (blockDim.x >> 6) + (threadIdx.x >> 6);
    if (wid >= n_nodes) return;
    int lane = threadIdx.x & 63;

    int s = offs[wid];
    int e = offs[wid + 1];
    float2 acc = make_float2(0.f, 0.f);

    int k = s;
    if ((k & 1) && k < e) {   // peel to even k -> 16B-aligned int4 loads
        int2 e0 = evec[k];
        unsigned u0 = *(const unsigned*)&hb[(size_t)e0.x * D + lane * 2];
        float v0 = __int_as_float(e0.y);
        acc.x += v0 * bf2f_lo(u0); acc.y += v0 * bf2f_hi(u0);
        ++k;
    }
    for (; k + 7 < e; k += 8) {
        int4 p0 = *(const int4*)&evec[k];
        int4 p1 = *(const int4*)&evec[k + 2];
        int4 p2 = *(const int4*)&evec[k + 4];
        int4 p3 = *(const int4*)&evec[k + 6];
        unsigned u0 = *(const unsigned*)&hb[(size_t)p0.x * D + lane * 2];
        unsigned u1 = *(const unsigned*)&hb[(size_t)p0.z * D + lane * 2];
        unsigned u2 = *(const unsigned*)&hb[(size_t)p1.x * D + lane * 2];
        unsigned u3 = *(const unsigned*)&hb[(size_t)p1.z * D + lane * 2];
        unsigned u4 = *(const unsigned*)&hb[(size_t)p2.x * D + lane * 2];
        unsigned u5 = *(const unsigned*)&hb[(size_t)p2.z * D + lane * 2];
        unsigned u6 = *(const unsigned*)&hb[(size_t)p3.x * D + lane * 2];
        unsigned u7 = *(const unsigned*)&hb[(size_t)p3.z * D + lane * 2];
        float v0 = __int_as_float(p0.y), v1 = __int_as_float(p0.w);
        float v2 = __int_as_float(p1.y), v3 = __int_as_float(p1.w);
        float v4 = __int_as_float(p2.y), v5 = __int_as_float(p2.w);
        float v6 = __int_as_float(p3.y), v7 = __int_as_float(p3.w);
        acc.x += v0 * bf2f_lo(u0); acc.y += v0 * bf2f_hi(u0);
        acc.x += v1 * bf2f_lo(u1); acc.y += v1 * bf2f_hi(u1);
        acc.x += v2 * bf2f_lo(u2); acc.y += v2 * bf2f_hi(u2);
        acc.x += v3 * bf2f_lo(u3); acc.y += v3 * bf2f_hi(u3);
        acc.x += v4 * bf2f_lo(u4); acc.y += v4 * bf2f_hi(u4);
        acc.x += v5 * bf2f_lo(u5); acc.y += v5 * bf2f_hi(u5);
        acc.x += v6 * bf2f_lo(u6); acc.y += v6 * bf2f_hi(u6);
        acc.x += v7 * bf2f_lo(u7); acc.y += v7 * bf2f_hi(u7);
    }
    for (; k + 1 < e; k += 2) {
        int4 p0 = *(const int4*)&evec[k];
        unsigned u0 = *(const unsigned*)&hb[(size_t)p0.x * D + lane * 2];
        unsigned u1 = *(const unsigned*)&hb[(size_t)p0.z * D + lane * 2];
        float v0 = __int_as_float(p0.y), v1 = __int_as_float(p0.w);
        acc.x += v0 * bf2f_lo(u0); acc.y += v0 * bf2f_hi(u0);
        acc.x += v1 * bf2f_lo(u1); acc.y += v1 * bf2f_hi(u1);
    }
    if (k < e) {
        int2 e0 = evec[k];
        unsigned u0 = *(const unsigned*)&hb[(size_t)e0.x * D + lane * 2];
        float v0 = __int_as_float(e0.y);
        acc.x += v0 * bf2f_lo(u0); acc.y += v0 * bf2f_hi(u0);
    }

    *(float2*)&out[(size_t)wid * D + lane * 2] = acc;
}

// ---------------------------------------------------------------- fallback
__global__ __launch_bounds__(256) void scatter_add(
    const int* __restrict__ rows, const int* __restrict__ cols,
    const float* __restrict__ vals, const unsigned short* __restrict__ hb,
    float* __restrict__ out, int n_edges) {
    long long gid = (long long)blockIdx.x * blockDim.x + threadIdx.x;
    int e  = (int)(gid >> 5);
    if (e >= n_edges) return;
    int d4 = ((int)gid & 31) * 4;
    int   r = rows[e];
    int   c = cols[e];
    float v = vals[e];
    const unsigned short* hp = &hb[(size_t)c * D + d4];
    unsigned u0 = *(const unsigned*)(hp + 0);
    unsigned u1 = *(const unsigned*)(hp + 2);
    float* op = &out[(size_t)r * D + d4];
    atomicAdd(op + 0, v * bf2f_lo(u0));
    atomicAdd(op + 1, v * bf2f_hi(u0));
    atomicAdd(op + 2, v * bf2f_lo(u1));
    atomicAdd(op + 3, v * bf2f_hi(u1));
}

__global__ void convert_W(const float* __restrict__ W, unsigned short* __restrict__ Wb) {
    int i = blockIdx.x * blockDim.x + threadIdx.x;
    if (i < D * D) Wb[i] = f2bf(W[i]);
}

__global__ __launch_bounds__(256) void gemm_mfma(
    const float* __restrict__ x, const unsigned short* __restrict__ Wb,
    const float* __restrict__ b, unsigned short* __restrict__ hb, int n_rows) {
    const int lane = threadIdx.x & 63;
    const int wv   = threadIdx.x >> 6;
    const int row0 = blockIdx.x * 64 + wv * 16;
    if (row0 >= n_rows) return;
    const int m  = lane & 15;
    const int kg = lane >> 4;
    int arow = row0 + m;
    if (arow >= n_rows) arow = n_rows - 1;
    const float* xr = x + (size_t)arow * D + kg * 8;
    f32x4 acc[8];
#pragma unroll
    for (int n = 0; n < 8; ++n) acc[n] = (f32x4){0.f, 0.f, 0.f, 0.f};
#pragma unroll
    for (int ks = 0; ks < 4; ++ks) {
        float4 f0 = *(const float4*)(xr + ks * 32);
        float4 f1 = *(const float4*)(xr + ks * 32 + 4);
        bf16x8 a;
        a[0] = (short)f2bf(f0.x); a[1] = (short)f2bf(f0.y);
        a[2] = (short)f2bf(f0.z); a[3] = (short)f2bf(f0.w);
        a[4] = (short)f2bf(f1.x); a[5] = (short)f2bf(f1.y);
        a[6] = (short)f2bf(f1.z); a[7] = (short)f2bf(f1.w);
#pragma unroll
        for (int n = 0; n < 8; ++n) {
            bf16x8 bf = *(const bf16x8*)&Wb[(size_t)(n * 16 + m) * D + ks * 32 + kg * 8];
            acc[n] = __builtin_amdgcn_mfma_f32_16x16x32_bf16(a, bf, acc[n], 0, 0, 0);
        }
    }
#pragma unroll
    for (int n = 0; n < 8; ++n) {
        int col = n * 16 + m;
        float bc = b[col];
#pragma unroll
        for (int j = 0; j < 4; ++j) {
            int r = row0 + kg * 4 + j;
            if (r < n_rows) hb[(size_t)r * D + col] = f2bf(acc[n][j] + bc);
        }
    }
}

// ---------------------------------------------------------------- launch
static inline size_t align16(size_t x) { return (x + 15) & ~(size_t)15; }

extern "C" void kernel_launch(void* const* d_in, const int* in_sizes, int n_in,
                              void* d_out, int out_size, void* d_ws, size_t ws_size,
                              hipStream_t stream) {
    const float* x    = (const float*)d_in[0];
    const int*   rows = (const int*)  d_in[1];
    const int*   cols = (const int*)  d_in[2];
    const float* vals = (const float*)d_in[3];
    const float* W    = (const float*)d_in[4];
    const float* b    = (const float*)d_in[5];
    float*       out  = (float*)d_out;

    const int n_nodes = in_sizes[0] / D;   // 50000
    const int n_edges = in_sizes[1];       // 800000
    const int nScanBlocks = (n_nodes + SCAN_BLK - 1) / SCAN_BLK;
    const int histBlocks  = (n_edges + 255) / 256;
    const int convBlocks  = (D * D + 255) / 256;
    const int gemmBlocks  = (n_nodes + 63) / 64;           // 782
    const int nGroups     = (gemmBlocks + 1) / 2;          // 391
    const int permSlots   = nGroups * 3;                   // 1173
    const int mainBlocks  = nGroups * 5;

    // ---- workspace layout (16B-aligned regions)
    char*  base    = (char*)d_ws;
    size_t off     = 0;
    unsigned short* Wb = (unsigned short*)(base + off); off = align16(off + (size_t)D * D * 2);
    unsigned short* hb = (unsigned short*)(base + off); off = align16(off + (size_t)n_nodes * D * 2);
    int*   counts  = (int*)  (base + off); off = align16(off + (size_t)n_nodes * 4);
    int*   offs    = (int*)  (base + off); off = align16(off + ((size_t)n_nodes + 1) * 4);
    int*   cursor  = (int*)  (base + off); off = align16(off + (size_t)n_nodes * 4);
    int*   bsums   = (int*)  (base + off); off = align16(off + (size_t)1024 * 4);
    int2*  evec    = (int2*) (base + off); off = align16(off + (size_t)n_edges * 8);
    const bool csr_fits = (off <= ws_size);

    if (csr_fits) {
        hipMemsetAsync(counts, 0, (size_t)n_nodes * 4, stream);
        fused_pre<<<histBlocks + convBlocks, 256, 0, stream>>>(
            rows, counts, n_edges, W, Wb, histBlocks);
        if (nScanBlocks <= 1024) {
            scan_local<<<nScanBlocks, SCAN_BLK, 0, stream>>>(counts, offs, bsums, n_nodes);
            scan_blocks<<<1, 1024, 0, stream>>>(bsums, &offs[n_nodes], nScanBlocks);
            scan_add<<<nScanBlocks, SCAN_BLK, 0, stream>>>(offs, cursor, bsums, n_nodes);
        } else {
            scan_counts<<<1, SCAN_THREADS, 0, stream>>>(counts, offs, cursor, n_nodes);
        }
        fused_main<<<mainBlocks, 256, 0, stream>>>(
            rows, cols, vals, cursor, evec, n_edges, permSlots,
            x, Wb, b, hb, n_nodes);
        aggregate<<<(n_nodes + 3) / 4, 256, 0, stream>>>(offs, evec, hb, out, n_nodes);
    } else {
        convert_W<<<convBlocks, 256, 0, stream>>>(W, Wb);
        gemm_mfma<<<gemmBlocks, 256, 0, stream>>>(x, Wb, b, hb, n_nodes);
        hipMemsetAsync(d_out, 0, (size_t)n_nodes * D * sizeof(float), stream);
        long long scatter_threads = (long long)n_edges * 32;
        int scatter_blocks = (int)((scatter_threads + 255) / 256);
        scatter_add<<<scatter_blocks, 256, 0, stream>>>(rows, cols, vals, hb, out, n_edges);
    }
}